// Round 4
// baseline (2196.138 us; speedup 1.0000x reference)
//
#include <hip/hip_runtime.h>
#include <hip/hip_fp16.h>

typedef _Float16 f16;
typedef __attribute__((ext_vector_type(8))) _Float16 f16x8;
typedef __attribute__((ext_vector_type(4))) _Float16 f16x4;
typedef __attribute__((ext_vector_type(4))) float f32x4;

#define D_      512
#define NG_     2048
#define B_      64
#define S_      256
#define C_      16
#define M_      (B_*S_)      // 16384

// ---- workspace layout (bytes) ----
#define OFF_X    0ull
#define SZ_X     ((unsigned long long)M_*D_*2)            // x fp16 [16384][512]
#define OFF_G    (OFF_X + SZ_X)
#define SZ_G     ((unsigned long long)M_*NG_*2)           // G2 fp16 [16384][512][4] gate-interleaved
#define OFF_WI   (OFF_G + SZ_G)
#define SZ_WI    ((unsigned long long)NG_*D_*2)           // W_ih fp16
#define OFF_HG   (OFF_WI + SZ_WI)
#define SZ_HG    (2ull*4*16*256*4)                        // h slab dbl-buf [2][4cl][16ch][256 uint]
#define OFF_FH   (OFF_HG + SZ_HG)
#define SZ_FH    ((unsigned long long)B_*D_*4)            // final_h f32 [64][512]
#define OFF_FL   (OFF_FH + SZ_FH)
#define SZ_FL    (32ull*64*4)                             // seq: 32 WGs x 64-uint stride
#define WS_NEED  (OFF_FL + SZ_FL)

__device__ __forceinline__ float sigmoidf_(float x) { return 1.f / (1.f + __expf(-x)); }
__device__ __forceinline__ float tanhf_(float x) {
  float a = fabsf(x);
  float e = __expf(-2.f * a);
  float r = (1.f - e) / (1.f + e);
  return copysignf(r, x);
}

// ---------------- K0: zero the seq flags ----------------
__global__ void k_zero(unsigned* __restrict__ p) {
  for (int i = threadIdx.x; i < 32 * 64; i += 256) p[i] = 0u;
}

// ---------------- K1: embedding gather + sum -> x fp16 ----------------
__global__ void k_embed(const int* __restrict__ seqs, const float* __restrict__ table,
                        f16* __restrict__ x) {
  const int m = blockIdx.x;
  const int t = threadIdx.x;
  const int* idx = seqs + (size_t)m * C_;
  float4 acc = {0.f, 0.f, 0.f, 0.f};
  #pragma unroll
  for (int r = 0; r < C_; ++r) {
    int id = idx[r];  // row VOCAB is all-zero in the provided table
    const float4* row = (const float4*)(table + (size_t)id * D_);
    float4 v = row[t];
    acc.x += v.x; acc.y += v.y; acc.z += v.z; acc.w += v.w;
  }
  f16x4 o;
  o[0] = (f16)acc.x; o[1] = (f16)acc.y; o[2] = (f16)acc.z; o[3] = (f16)acc.w;
  *(f16x4*)(x + (size_t)m * D_ + t * 4) = o;
}

// ---------------- K1b: convert W_ih fp32 -> fp16 ----------------
__global__ void k_cvtw(const float* __restrict__ w, f16* __restrict__ o, int n) {
  int i = blockIdx.x * 256 + threadIdx.x;
  if (i < n) o[i] = (f16)w[i];
}

// ---------------- K2: G2 = x @ W_ih^T, gate-interleaved output ----------------
// grid (32 ntiles, 256 mtiles) x 256 thr: XCD = bid%8 = nt%8 -> each XCD keeps a
// fixed 4-ntile wi slice (256KB) L2-resident. Output layout: G2[m][col][gate],
// col = n&511, gate = n>>9 -> recurrence epilogue reads one f16x4 per chain.
__global__ void k_gemm_ih(const f16* __restrict__ x, const f16* __restrict__ wi,
                          f16* __restrict__ G2) {
  const int nt = blockIdx.x, mt = blockIdx.y;
  const int wid = threadIdx.x >> 6, lane = threadIdx.x & 63;
  const int lr = lane & 15, lq = lane >> 4;
  const int m0 = mt * 64 + wid * 16;
  const int n0 = nt * 64;
  const int gate = nt >> 3;
  const int cbase = (nt & 7) * 64;  // within-gate col base

  f32x4 acc[4] = {{0.f,0.f,0.f,0.f},{0.f,0.f,0.f,0.f},{0.f,0.f,0.f,0.f},{0.f,0.f,0.f,0.f}};
  for (int kt = 0; kt < 16; ++kt) {
    const int k0 = kt * 32 + lq * 8;
    const f16x8 a = *(const f16x8*)(x + (size_t)(m0 + lr) * D_ + k0);
    #pragma unroll
    for (int j = 0; j < 4; ++j) {
      const f16x8 b = *(const f16x8*)(wi + (size_t)(n0 + j * 16 + lr) * D_ + k0);
      acc[j] = __builtin_amdgcn_mfma_f32_16x16x32_f16(a, b, acc[j], 0, 0, 0);
    }
  }
  // D mapping: col = lane&15 (n), row = (lane>>4)*4 + reg (m)
  #pragma unroll
  for (int j = 0; j < 4; ++j)
    #pragma unroll
    for (int rr = 0; rr < 4; ++rr) {
      const int m = m0 + lq * 4 + rr;
      const int col = cbase + j * 16 + lr;
      G2[(size_t)m * NG_ + col * 4 + gate] = (f16)acc[j][rr];
    }
}

// ---------------- K3: LSTM recurrence ----------------
// 32 WGs x 512 thr. cluster cl = bid&3 (8 WGs, 16 chains); rank r = bid>>2 (0..7).
// WG owns 256 W_hh rows (h-idx [r*64,r*64+64) x 4 gates) as persistent VGPR B-frags
// (128 VGPR). Sync: per-WG seq word (release store, no RMW); wave w polls exactly
// producer-WG w's seq, then gathers its k-slice -- no barrier between poll & gather.
// Safety of dbl-buf reuse distance 2: a WG reaches its step t+2 slab write only
// after all 8 waves saw ALL cluster flags >= t+2; WG q's flag hits t+2 only after
// q's step-t gather of buffer t&1 completed. So no overwrite-before-read.
__global__ __launch_bounds__(512, 1) void k_lstm(
    const float* __restrict__ whh, const f16* __restrict__ G2,
    const int* __restrict__ lengths, unsigned* __restrict__ hGu,
    unsigned* __restrict__ seq, float* __restrict__ final_h) {
  const int bid = blockIdx.x;
  const int cl = bid & 3;
  const int r = bid >> 2;          // 0..7
  const int tid = threadIdx.x;
  const int wid = tid >> 6, lane = tid & 63;
  const int lr = lane & 15, lq = lane >> 4;

  __shared__ f16 h_lds[16][522];     // 261 dwords/row; 261%32=5 -> banks spread
  __shared__ float glds[4][64][21];  // [gate][h-idx in WG][chain], odd pad -> 2-way reads
  __shared__ int steps_sh;

  // persistent W_hh B-frags: wave wid owns n_local [wid*32, wid*32+32)
  f16x8 wf0[16], wf1[16];
  {
    const int nl0 = wid * 32 + lr;
    const int nl1 = nl0 + 16;
    const int row0 = (nl0 >> 6) * 512 + r * 64 + (nl0 & 63);
    const int row1 = (nl1 >> 6) * 512 + r * 64 + (nl1 & 63);
    for (int kt = 0; kt < 16; ++kt) {
      const int k0 = kt * 32 + lq * 8;
      const float* p0 = whh + (size_t)row0 * D_ + k0;
      const float* p1 = whh + (size_t)row1 * D_ + k0;
      f16x8 w0, w1;
      #pragma unroll
      for (int e = 0; e < 8; ++e) { w0[e] = (f16)p0[e]; w1[e] = (f16)p1[e]; }
      wf0[kt] = w0; wf1[kt] = w1;
    }
  }
  for (int i = tid; i < 16 * 522; i += 512) ((f16*)h_lds)[i] = (f16)0.f;

  // epilogue mapping: wave wid handles chains {wid, wid+8}, lane = h-col ej
  const int ej = lane;
  const int ec0 = wid;
  const int b0 = cl * 16 + ec0, b1 = b0 + 8;
  const int len0 = lengths[b0], len1 = lengths[b1];

  if (tid == 0) {
    int mx = 0;
    for (int c = 0; c < 16; ++c) mx = max(mx, lengths[cl * 16 + c]);
    steps_sh = mx;
  }
  float cs0 = 0.f, cs1 = 0.f;
  __syncthreads();
  const int steps = steps_sh;

  // gather mapping: chain gc = tid&15, k-slot gq = tid>>4 (16 f16 each).
  // producer of k-range [gq*16,(gq+1)*16) is WG gq>>2 == wid (uniform per wave).
  const int gc = tid & 15;
  const int gq = tid >> 4;
  unsigned* pollflag = seq + (cl * 8 + (gq >> 2)) * 64;
  unsigned* wgflag = seq + (cl * 8 + r) * 64;

  const size_t gb0 = (size_t)b0 * S_ * NG_ + (r * 64 + ej) * 4;
  const size_t gb1 = (size_t)b1 * S_ * NG_ + (r * 64 + ej) * 4;
  f16x4 gfa = *(const f16x4*)(G2 + gb0);   // t = 0 prefetch
  f16x4 gfb = *(const f16x4*)(G2 + gb1);

  for (int t = 0; t < steps; ++t) {
    // 1. MFMA: two independent 16-deep chains
    f32x4 acc0 = {0.f,0.f,0.f,0.f}, acc1 = {0.f,0.f,0.f,0.f};
    #pragma unroll
    for (int kt = 0; kt < 16; ++kt) {
      const f16x8 a = *(const f16x8*)&h_lds[lr][kt * 32 + lq * 8];
      acc0 = __builtin_amdgcn_mfma_f32_16x16x32_f16(a, wf0[kt], acc0, 0, 0, 0);
      acc1 = __builtin_amdgcn_mfma_f32_16x16x32_f16(a, wf1[kt], acc1, 0, 0, 0);
    }
    {
      const int nl0 = wid * 32 + lr, nl1 = nl0 + 16;
      #pragma unroll
      for (int rr = 0; rr < 4; ++rr) {
        glds[nl0 >> 6][nl0 & 63][lq * 4 + rr] = acc0[rr];
        glds[nl1 >> 6][nl1 & 63][lq * 4 + rr] = acc1[rr];
      }
    }
    __syncthreads();  // barrier 1: glds ready

    // 2. epilogue: 2 chains per thread
    {
      float ig = glds[0][ej][ec0] + (float)gfa[0];
      float fg = glds[1][ej][ec0] + (float)gfa[1];
      float gg = glds[2][ej][ec0] + (float)gfa[2];
      float og = glds[3][ej][ec0] + (float)gfa[3];
      ig = sigmoidf_(ig); fg = sigmoidf_(fg); og = sigmoidf_(og); gg = tanhf_(gg);
      cs0 = fg * cs0 + ig * gg;
      const float hv0 = og * tanhf_(cs0);
      if (t == len0 - 1) final_h[(size_t)b0 * D_ + r * 64 + ej] = hv0;

      float ig1 = glds[0][ej][ec0 + 8] + (float)gfb[0];
      float fg1 = glds[1][ej][ec0 + 8] + (float)gfb[1];
      float gg1 = glds[2][ej][ec0 + 8] + (float)gfb[2];
      float og1 = glds[3][ej][ec0 + 8] + (float)gfb[3];
      ig1 = sigmoidf_(ig1); fg1 = sigmoidf_(fg1); og1 = sigmoidf_(og1); gg1 = tanhf_(gg1);
      cs1 = fg1 * cs1 + ig1 * gg1;
      const float hv1 = og1 * tanhf_(cs1);
      if (t == len1 - 1) final_h[(size_t)b1 * D_ + r * 64 + ej] = hv1;

      // pack pairs (ej, ej^1) and store to slab, agent scope
      unsigned h0 = (unsigned)(unsigned short)__builtin_bit_cast(unsigned short, (f16)hv0);
      unsigned h1 = (unsigned)(unsigned short)__builtin_bit_cast(unsigned short, (f16)hv1);
      unsigned o0 = __shfl_xor(h0, 1);
      unsigned o1 = __shfl_xor(h1, 1);
      if (!(ej & 1)) {
        const size_t sb = (size_t)(t & 1) * 16384 + cl * 4096;
        const int kp = r * 32 + (ej >> 1);
        __hip_atomic_store(&hGu[sb + ec0 * 256 + kp],
                           h0 | (o0 << 16), __ATOMIC_RELAXED, __HIP_MEMORY_SCOPE_AGENT);
        __hip_atomic_store(&hGu[sb + (ec0 + 8) * 256 + kp],
                           h1 | (o1 << 16), __ATOMIC_RELAXED, __HIP_MEMORY_SCOPE_AGENT);
      }
    }

    // 3. prefetch next-step G (latency hides under the store-drain barrier)
    {
      const int tn = min(t + 1, S_ - 1);
      gfa = *(const f16x4*)(G2 + gb0 + (size_t)tn * NG_);
      gfb = *(const f16x4*)(G2 + gb1 + (size_t)tn * NG_);
    }
    __syncthreads();  // barrier 2: all slab stores drained (vmcnt 0 per wave)

    if (tid == 0)
      __hip_atomic_store(wgflag, (unsigned)(t + 1), __ATOMIC_RELEASE, __HIP_MEMORY_SCOPE_AGENT);

    // 4. poll producer WG's seq (wave-uniform address), then gather immediately
    while (__hip_atomic_load(pollflag, __ATOMIC_ACQUIRE, __HIP_MEMORY_SCOPE_AGENT)
           < (unsigned)(t + 1))
      __builtin_amdgcn_s_sleep(1);
    {
      const size_t base = (size_t)(t & 1) * 16384 + cl * 4096 + gc * 256 + gq * 8;
      unsigned v[8];
      #pragma unroll
      for (int e = 0; e < 8; ++e)
        v[e] = __hip_atomic_load(&hGu[base + e], __ATOMIC_RELAXED, __HIP_MEMORY_SCOPE_AGENT);
      unsigned* dst = (unsigned*)&h_lds[gc][gq * 16];
      #pragma unroll
      for (int e = 0; e < 8; ++e) dst[e] = v[e];
    }
    __syncthreads();  // barrier 3: h(t) in LDS for next step
  }
}

// ---------------- K4: out = final_h @ w_out^T + b_out ----------------
__global__ void k_head(const float* __restrict__ fh, const float* __restrict__ wout,
                       const float* __restrict__ bout, float* __restrict__ out) {
  const int b = blockIdx.x;
  const int lane = threadIdx.x;  // 64
  float p0 = 0.f, p1 = 0.f;
  for (int k = lane; k < D_; k += 64) {
    const float h = fh[(size_t)b * D_ + k];
    p0 += h * wout[k];
    p1 += h * wout[D_ + k];
  }
  #pragma unroll
  for (int off = 32; off; off >>= 1) {
    p0 += __shfl_down(p0, off);
    p1 += __shfl_down(p1, off);
  }
  if (lane == 0) {
    out[b * 2 + 0] = p0 + bout[0];
    out[b * 2 + 1] = p1 + bout[1];
  }
}

extern "C" void kernel_launch(void* const* d_in, const int* in_sizes, int n_in,
                              void* d_out, int out_size, void* d_ws, size_t ws_size,
                              hipStream_t stream) {
  const int* seqs = (const int*)d_in[0];
  const int* lengths = (const int*)d_in[1];
  const float* table = (const float*)d_in[2];
  const float* wih = (const float*)d_in[3];
  const float* whh = (const float*)d_in[4];
  const float* wout = (const float*)d_in[5];
  const float* bout = (const float*)d_in[6];
  float* out = (float*)d_out;
  char* ws = (char*)d_ws;
  if (ws_size < WS_NEED) return;

  f16* x = (f16*)(ws + OFF_X);
  f16* G2 = (f16*)(ws + OFF_G);
  f16* wi16 = (f16*)(ws + OFF_WI);
  unsigned* hGu = (unsigned*)(ws + OFF_HG);
  float* fh = (float*)(ws + OFF_FH);
  unsigned* seqf = (unsigned*)(ws + OFF_FL);

  hipLaunchKernelGGL(k_zero, dim3(1), dim3(256), 0, stream, seqf);
  hipLaunchKernelGGL(k_embed, dim3(M_), dim3(128), 0, stream, seqs, table, x);
  hipLaunchKernelGGL(k_cvtw, dim3((NG_ * D_ + 255) / 256), dim3(256), 0, stream,
                     wih, wi16, NG_ * D_);
  hipLaunchKernelGGL(k_gemm_ih, dim3(NG_ / 64, M_ / 64), dim3(256), 0, stream, x, wi16, G2);
  hipLaunchKernelGGL(k_lstm, dim3(32), dim3(512), 0, stream, whh, G2, lengths, hGu, seqf, fh);
  hipLaunchKernelGGL(k_head, dim3(B_), dim3(64), 0, stream, fh, wout, bout, out);
}